// Round 2
// baseline (201.203 us; speedup 1.0000x reference)
//
#include <hip/hip_runtime.h>
#include <hip/hip_bf16.h>

#define EMBED 256
#define LL 6   // layers

// ---------------- calib = inv(rt^T) in double, 1 thread ----------------
__global__ void k_calib(const float* __restrict__ rt, float* __restrict__ calib) {
    if (threadIdx.x != 0 || blockIdx.x != 0) return;
    double a[4][8];
    for (int i = 0; i < 4; ++i)
        for (int j = 0; j < 4; ++j) {
            a[i][j]     = (double)rt[j * 4 + i];   // M = rt^T
            a[i][4 + j] = (i == j) ? 1.0 : 0.0;
        }
    for (int c = 0; c < 4; ++c) {
        int p = c; double best = fabs(a[c][c]);
        for (int r = c + 1; r < 4; ++r) { double v = fabs(a[r][c]); if (v > best) { best = v; p = r; } }
        if (p != c) for (int j = 0; j < 8; ++j) { double t = a[c][j]; a[c][j] = a[p][j]; a[p][j] = t; }
        double inv = 1.0 / a[c][c];
        for (int j = 0; j < 8; ++j) a[c][j] *= inv;
        for (int r = 0; r < 4; ++r) if (r != c) {
            double f = a[r][c];
            for (int j = 0; j < 8; ++j) a[r][j] -= f * a[c][j];
        }
    }
    for (int i = 0; i < 4; ++i)
        for (int j = 0; j < 4; ++j) calib[i * 4 + j] = (float)a[i][4 + j];
}

// ---------------- predicate + compaction (single block scan) ----------------
__global__ void k_select(const float* __restrict__ cls, int n,
                         int* __restrict__ bbox, int* __restrict__ cnt) {
    __shared__ int sd[1024];
    __shared__ int s_base;
    int tid = threadIdx.x;
    if (tid == 0) s_base = 0;
    __syncthreads();
    for (int base = 0; base < n; base += 1024) {
        int i = base + tid;
        int pred = 0;
        if (i < n) {
            float x = cls[i];
            float s = 1.0f / (1.0f + expf(-x));
            pred = (s > 0.05f) ? 1 : 0;
        }
        sd[tid] = pred;
        __syncthreads();
        for (int off = 1; off < 1024; off <<= 1) {
            int v = (tid >= off) ? sd[tid - off] : 0;
            __syncthreads();
            sd[tid] += v;
            __syncthreads();
        }
        if (pred) bbox[s_base + sd[tid] - 1] = i / 3;
        int tot = sd[1023];
        __syncthreads();
        if (tid == 0) s_base += tot;
        __syncthreads();
    }
    if (tid == 0) *cnt = s_base;
}

// ---------------- bvec[j] = b[j] + sum_u r[u]*W[256+u][j] ----------------
__global__ void k_bvec(const float* __restrict__ calib,
                       const float* __restrict__ W0, const float* __restrict__ b0,
                       const float* __restrict__ W1, const float* __restrict__ b1,
                       float* __restrict__ bvec0, float* __restrict__ bvec1) {
    int which = blockIdx.x;
    int j = threadIdx.x;
    const float* W = which ? W1 : W0;
    const float* b = which ? b1 : b0;
    float* o = which ? bvec1 : bvec0;
    float s = b[j];
#pragma unroll
    for (int u = 0; u < 9; ++u) {
        float r = calib[(u / 3) * 4 + (u % 3)];
        s += r * W[(EMBED + u) * EMBED + j];
    }
    o[j] = s;
}

// ---------------- veh layered copy, float4 (rowlen*NV divisible by 4) ----------------
__global__ void k_veh_lay4(const float* __restrict__ src, float* __restrict__ out,
                           int n4, int N_rowlen, int NV_rowlen, int off) {
    int l = blockIdx.y;
    int i = blockIdx.x * blockDim.x + threadIdx.x;
    if (i >= n4) return;
    float4 v = *(const float4*)&src[(size_t)l * NV_rowlen + 4 * i];
    *(float4*)&out[off + (size_t)l * N_rowlen + 4 * i] = v;
}

// ---------------- plain contiguous float4 copy ----------------
__global__ void k_copy4(const float* __restrict__ src, float* __restrict__ out,
                        int n4, int off) {
    int i = blockIdx.x * blockDim.x + threadIdx.x;
    if (i < n4) *(float4*)&out[off + 4 * (size_t)i] = *(const float4*)&src[4 * (size_t)i];
}

// ---------------- inf classes gather (per element) ----------------
__global__ void k_inf_cls(const float* __restrict__ src, const int* __restrict__ bbox,
                          float* __restrict__ out,
                          int NI, int NV, int K, int N, int off) {
    int l = blockIdx.y;
    int i = blockIdx.x * blockDim.x + threadIdx.x;
    if (i >= K * 3) return;
    int k = i / 3, c = i - k * 3;
    int box = bbox[k]; box = max(0, min(box, NI - 1));
    out[off + ((size_t)l * N + NV) * 3 + i] = src[((size_t)l * NI + box) * 3 + c];
}

// ---------------- inf coords gather + transform ----------------
__global__ void k_inf_coord(const float* __restrict__ src, const int* __restrict__ bbox,
                            const float* __restrict__ calib,
                            float* __restrict__ out,
                            int NI, int NV, int K, int N, int off) {
    int l = blockIdx.y;
    int k = blockIdx.x * blockDim.x + threadIdx.x;
    if (k >= K) return;
    int box = bbox[k]; box = max(0, min(box, NI - 1));
    const float* s = src + ((size_t)l * NI + box) * 4;
    float c0 = s[0], c1 = s[1], c2 = s[2], c3 = s[3];
    // norm2lidar (INF_PC_RANGE), z = 0 -> -5
    float X = c0 * 102.4f;
    float Y = c1 * 102.4f - 51.2f;
    float Z = -5.0f;
    float tx = calib[0] * X + calib[1] * Y + calib[2] * Z + calib[3];
    float ty = calib[4] * X + calib[5] * Y + calib[6] * Z + calib[7];
    // lidar2norm (PC_RANGE)
    float nx = (tx + 51.2f) * (1.0f / 102.4f);
    float ny = (ty + 51.2f) * (1.0f / 102.4f);
    float4 v = make_float4(nx, ny, c2, c3);
    *(float4*)&out[off + ((size_t)l * N + NV + k) * 4] = v;
}

// ---------------- inf reference gather + sigmoid/transform/inv-sigmoid ----------------
__device__ __forceinline__ float inv_sig(float v) {
    v = fminf(fmaxf(v, 0.0f), 1.0f);
    float x1 = fmaxf(v, 1e-5f);
    float x2 = fmaxf(1.0f - v, 1e-5f);
    return logf(x1 / x2);
}

__global__ void k_inf_ref(const float* __restrict__ src, const int* __restrict__ bbox,
                          const float* __restrict__ calib,
                          float* __restrict__ out,
                          int NI, int NV, int K, int off) {
    int k = blockIdx.x * blockDim.x + threadIdx.x;
    if (k >= K) return;
    int box = bbox[k]; box = max(0, min(box, NI - 1));
    const float* s = src + (size_t)box * 4;
    float r0 = s[0], r1 = s[1], r2 = s[2], r3 = s[3];
    float sx = 1.0f / (1.0f + expf(-r0));
    float sy = 1.0f / (1.0f + expf(-r1));
    // sz = sigmoid(0) = 0.5 -> lidar z = 0.5*8-5 = -1
    float X = sx * 102.4f;
    float Y = sy * 102.4f - 51.2f;
    float Z = -1.0f;
    float tx = calib[0] * X + calib[1] * Y + calib[2] * Z + calib[3];
    float ty = calib[4] * X + calib[5] * Y + calib[6] * Z + calib[7];
    float nx = (tx + 51.2f) * (1.0f / 102.4f);
    float ny = (ty + 51.2f) * (1.0f / 102.4f);
    float4 v = make_float4(inv_sig(nx), inv_sig(ny), r2, r3);
    *(float4*)&out[off + ((size_t)NV + k) * 4] = v;
}

// ---------------- GEMM: out[k][j] = q[box_k] . W[:,j] + bvec[j] ----------------
// block = 256 threads = 4 row-groups x 64 col-lanes; 64 rows/block staged in LDS.
__global__ __launch_bounds__(256) void k_gemm(const float* __restrict__ q,
                                              const int* __restrict__ bbox,
                                              const float* __restrict__ W,
                                              const float* __restrict__ bvec,
                                              float* __restrict__ out,
                                              int NI, int K, int out_off) {
    __shared__ float As[64][EMBED];   // 64 KB
    int r0 = blockIdx.x * 64;
    int tid = threadIdx.x;
    for (int s = 0; s < 64; ++s) {
        int row = r0 + s;
        float v = 0.0f;
        if (row < K) {
            int box = bbox[row]; box = max(0, min(box, NI - 1));
            v = q[(size_t)box * EMBED + tid];
        }
        As[s][tid] = v;
    }
    __syncthreads();

    int g = tid >> 6;       // row-group 0..3  (== wave id)
    int c = tid & 63;       // col-lane
    int col = c * 4;
    float4 bv = *(const float4*)&bvec[col];
    float acc[16][4];
#pragma unroll
    for (int rr = 0; rr < 16; ++rr) {
        acc[rr][0] = bv.x; acc[rr][1] = bv.y; acc[rr][2] = bv.z; acc[rr][3] = bv.w;
    }
    for (int t4 = 0; t4 < EMBED / 4; ++t4) {
        float4 w0 = *(const float4*)&W[(4 * t4 + 0) * EMBED + col];
        float4 w1 = *(const float4*)&W[(4 * t4 + 1) * EMBED + col];
        float4 w2 = *(const float4*)&W[(4 * t4 + 2) * EMBED + col];
        float4 w3 = *(const float4*)&W[(4 * t4 + 3) * EMBED + col];
#pragma unroll
        for (int rr = 0; rr < 16; ++rr) {
            float4 a = *(const float4*)&As[g * 16 + rr][t4 * 4];
            acc[rr][0] = fmaf(a.w, w3.x, fmaf(a.z, w2.x, fmaf(a.y, w1.x, fmaf(a.x, w0.x, acc[rr][0]))));
            acc[rr][1] = fmaf(a.w, w3.y, fmaf(a.z, w2.y, fmaf(a.y, w1.y, fmaf(a.x, w0.y, acc[rr][1]))));
            acc[rr][2] = fmaf(a.w, w3.z, fmaf(a.z, w2.z, fmaf(a.y, w1.z, fmaf(a.x, w0.z, acc[rr][2]))));
            acc[rr][3] = fmaf(a.w, w3.w, fmaf(a.z, w2.w, fmaf(a.y, w1.w, fmaf(a.x, w0.w, acc[rr][3]))));
        }
    }
#pragma unroll
    for (int rr = 0; rr < 16; ++rr) {
        int row = r0 + g * 16 + rr;
        if (row < K) {
            float4 v = make_float4(acc[rr][0], acc[rr][1], acc[rr][2], acc[rr][3]);
            *(float4*)&out[out_off + (size_t)row * EMBED + col] = v;
        }
    }
}

extern "C" void kernel_launch(void* const* d_in, const int* in_sizes, int n_in,
                              void* d_out, int out_size, void* d_ws, size_t ws_size,
                              hipStream_t stream) {
    const float* inf_cls   = (const float*)d_in[0];
    const float* inf_coord = (const float*)d_in[1];
    const float* inf_q     = (const float*)d_in[2];
    const float* inf_qp    = (const float*)d_in[3];
    const float* inf_ref   = (const float*)d_in[4];
    const float* veh_cls   = (const float*)d_in[5];
    const float* veh_coord = (const float*)d_in[6];
    const float* veh_q     = (const float*)d_in[7];
    const float* veh_qp    = (const float*)d_in[8];
    const float* veh_ref   = (const float*)d_in[9];
    const float* rt        = (const float*)d_in[10];
    const float* W0        = (const float*)d_in[11];
    const float* b0        = (const float*)d_in[12];
    const float* W1        = (const float*)d_in[13];
    const float* b1        = (const float*)d_in[14];
    float* out = (float*)d_out;

    int NI = in_sizes[0] / (LL * 3);
    int NV = in_sizes[5] / (LL * 3);
    int N  = out_size / 558;          // 558 = 6*3 + 6*4 + 256 + 256 + 4
    int K  = N - NV;

    // output section element-offsets (f32 elements)
    int off_cls   = 0;
    int off_coord = LL * N * 3;
    int off_q     = off_coord + LL * N * 4;
    int off_qp    = off_q + N * EMBED;
    int off_ref   = off_qp + N * EMBED;

    // workspace layout
    char* ws = (char*)d_ws;
    float* calib = (float*)(ws);            // 16 floats
    float* bvec0 = (float*)(ws + 128);      // 256 floats
    float* bvec1 = (float*)(ws + 1152);     // 256 floats
    int*   cnt   = (int*)(ws + 2176);
    int*   bbox  = (int*)(ws + 2304);       // NI*3 ints max

    hipLaunchKernelGGL(k_calib, dim3(1), dim3(1), 0, stream, rt, calib);
    hipLaunchKernelGGL(k_select, dim3(1), dim3(1024), 0, stream,
                       inf_cls + (size_t)(LL - 1) * NI * 3, NI * 3, bbox, cnt);
    hipLaunchKernelGGL(k_bvec, dim3(2), dim3(EMBED), 0, stream,
                       calib, W0, b0, W1, b1, bvec0, bvec1);

    // veh copies (all section bases and lengths are multiples of 4 elements)
    {
        int n3_4 = NV * 3 / 4, n4_4 = NV * 4 / 4;
        hipLaunchKernelGGL(k_veh_lay4, dim3((n3_4 + 255) / 256, LL), dim3(256), 0, stream,
                           veh_cls, out, n3_4, N * 3, NV * 3, off_cls);
        hipLaunchKernelGGL(k_veh_lay4, dim3((n4_4 + 255) / 256, LL), dim3(256), 0, stream,
                           veh_coord, out, n4_4, N * 4, NV * 4, off_coord);
        int nq4 = NV * EMBED / 4;
        hipLaunchKernelGGL(k_copy4, dim3((nq4 + 255) / 256), dim3(256), 0, stream,
                           veh_q, out, nq4, off_q);
        hipLaunchKernelGGL(k_copy4, dim3((nq4 + 255) / 256), dim3(256), 0, stream,
                           veh_qp, out, nq4, off_qp);
        hipLaunchKernelGGL(k_copy4, dim3((n4_4 + 255) / 256), dim3(256), 0, stream,
                           veh_ref, out, n4_4, off_ref);
    }

    if (K > 0) {
        hipLaunchKernelGGL(k_inf_cls, dim3((K * 3 + 255) / 256, LL), dim3(256), 0, stream,
                           inf_cls, bbox, out, NI, NV, K, N, off_cls);
        hipLaunchKernelGGL(k_inf_coord, dim3((K + 255) / 256, LL), dim3(256), 0, stream,
                           inf_coord, bbox, calib, out, NI, NV, K, N, off_coord);
        hipLaunchKernelGGL(k_inf_ref, dim3((K + 255) / 256), dim3(256), 0, stream,
                           inf_ref, bbox, calib, out, NI, NV, K, off_ref);
        int gb = (K + 63) / 64;
        hipLaunchKernelGGL(k_gemm, dim3(gb), dim3(256), 0, stream,
                           inf_q, bbox, W0, bvec0, out, NI, K, off_q + NV * EMBED);
        hipLaunchKernelGGL(k_gemm, dim3(gb), dim3(256), 0, stream,
                           inf_qp, bbox, W1, bvec1, out, NI, K, off_qp + NV * EMBED);
    }
}

// Round 3
// 91.868 us; speedup vs baseline: 2.1901x; 2.1901x over previous
//
#include <hip/hip_runtime.h>
#include <hip/hip_bf16.h>

#define EMBED 256
#define LL 6   // layers

typedef __attribute__((ext_vector_type(8))) __bf16 bf16x8;
typedef __attribute__((ext_vector_type(4))) float f32x4;

// ---------------- calib = inv(rt^T) in double, 1 thread ----------------
__global__ void k_calib(const float* __restrict__ rt, float* __restrict__ calib) {
    if (threadIdx.x != 0 || blockIdx.x != 0) return;
    double a[4][8];
    for (int i = 0; i < 4; ++i)
        for (int j = 0; j < 4; ++j) {
            a[i][j]     = (double)rt[j * 4 + i];   // M = rt^T
            a[i][4 + j] = (i == j) ? 1.0 : 0.0;
        }
    for (int c = 0; c < 4; ++c) {
        int p = c; double best = fabs(a[c][c]);
        for (int r = c + 1; r < 4; ++r) { double v = fabs(a[r][c]); if (v > best) { best = v; p = r; } }
        if (p != c) for (int j = 0; j < 8; ++j) { double t = a[c][j]; a[c][j] = a[p][j]; a[p][j] = t; }
        double inv = 1.0 / a[c][c];
        for (int j = 0; j < 8; ++j) a[c][j] *= inv;
        for (int r = 0; r < 4; ++r) if (r != c) {
            double f = a[r][c];
            for (int j = 0; j < 8; ++j) a[r][j] -= f * a[c][j];
        }
    }
    for (int i = 0; i < 4; ++i)
        for (int j = 0; j < 4; ++j) calib[i * 4 + j] = (float)a[i][4 + j];
}

// ---------------- predicate + compaction: ballot-based single-block scan ----------------
__global__ void k_select(const float* __restrict__ cls, int n,
                         int* __restrict__ bbox, int* __restrict__ cnt) {
    __shared__ int warpCnt[16];
    __shared__ int s_base;
    int tid = threadIdx.x;
    int wid = tid >> 6, lane = tid & 63;
    if (tid == 0) s_base = 0;
    __syncthreads();
    float x = (tid < n) ? cls[tid] : -1e30f;
    for (int base = 0; base < n; base += 1024) {
        int nxt = base + 1024 + tid;
        float xn = (nxt < n) ? cls[nxt] : -1e30f;   // prefetch next chunk
        int i = base + tid;
        bool pred = false;
        if (i < n) {
            float s = 1.0f / (1.0f + expf(-x));
            pred = (s > 0.05f);
        }
        unsigned long long m = __ballot(pred);
        int prefix = __popcll(m & ((1ull << lane) - 1ull));
        if (lane == 0) warpCnt[wid] = __popcll(m);
        __syncthreads();
        int woff = 0;
        for (int w2 = 0; w2 < wid; ++w2) woff += warpCnt[w2];
        if (pred) bbox[s_base + woff + prefix] = i / 3;
        __syncthreads();
        if (tid == 0) {
            int tot = 0;
            for (int w2 = 0; w2 < 16; ++w2) tot += warpCnt[w2];
            s_base += tot;
        }
        __syncthreads();
        x = xn;
    }
    if (tid == 0) *cnt = s_base;
}

// ---------------- bvec[j] = b[j] + sum_u r[u]*W[256+u][j] ----------------
__global__ void k_bvec(const float* __restrict__ calib,
                       const float* __restrict__ W0, const float* __restrict__ b0,
                       const float* __restrict__ W1, const float* __restrict__ b1,
                       float* __restrict__ bvec0, float* __restrict__ bvec1) {
    int which = blockIdx.x;
    int j = threadIdx.x;
    const float* W = which ? W1 : W0;
    const float* b = which ? b1 : b0;
    float* o = which ? bvec1 : bvec0;
    float s = b[j];
#pragma unroll
    for (int u = 0; u < 9; ++u) {
        float r = calib[(u / 3) * 4 + (u % 3)];
        s += r * W[(EMBED + u) * EMBED + j];
    }
    o[j] = s;
}

// ---------------- W transpose + bf16: Wt[col][k] = bf16(W[k][col]) ----------------
__global__ void k_wprep(const float* __restrict__ W0, const float* __restrict__ W1,
                        __bf16* __restrict__ Wt0, __bf16* __restrict__ Wt1) {
    int col = blockIdx.x;                     // 0..255
    const float* W = blockIdx.y ? W1 : W0;
    __bf16* Wt = blockIdx.y ? Wt1 : Wt0;
    int k = threadIdx.x;                      // 0..255
    Wt[col * EMBED + k] = (__bf16)W[(size_t)k * EMBED + col];
}

// ---------------- fused veh copies (5 jobs, float4) ----------------
struct CopyJobs {
    const float* src[5];
    int n4[5];        // total float4 count
    int off[5];       // dst base (f32 elements)
    int perLay4[5];   // float4 per layer
    int layStride[5]; // dst layer stride (f32 elements)
};

__global__ void k_vehcopy(CopyJobs J, float* __restrict__ out) {
    int j = blockIdx.y;
    int i = blockIdx.x * blockDim.x + threadIdx.x;
    if (i >= J.n4[j]) return;
    int l = i / J.perLay4[j];
    int r = i - l * J.perLay4[j];
    float4 v = *(const float4*)&J.src[j][(size_t)i * 4];
    *(float4*)&out[(size_t)J.off[j] + (size_t)l * J.layStride[j] + (size_t)r * 4] = v;
}

// ---------------- inf classes gather ----------------
__global__ void k_inf_cls(const float* __restrict__ src, const int* __restrict__ bbox,
                          float* __restrict__ out,
                          int NI, int NV, int K, int N, int off) {
    int l = blockIdx.y;
    int i = blockIdx.x * blockDim.x + threadIdx.x;
    if (i >= K * 3) return;
    int k = i / 3, c = i - k * 3;
    int box = bbox[k]; box = max(0, min(box, NI - 1));
    out[off + ((size_t)l * N + NV) * 3 + i] = src[((size_t)l * NI + box) * 3 + c];
}

// ---------------- inf coords gather + transform ----------------
__global__ void k_inf_coord(const float* __restrict__ src, const int* __restrict__ bbox,
                            const float* __restrict__ calib,
                            float* __restrict__ out,
                            int NI, int NV, int K, int N, int off) {
    int l = blockIdx.y;
    int k = blockIdx.x * blockDim.x + threadIdx.x;
    if (k >= K) return;
    int box = bbox[k]; box = max(0, min(box, NI - 1));
    const float* s = src + ((size_t)l * NI + box) * 4;
    float c0 = s[0], c1 = s[1], c2 = s[2], c3 = s[3];
    float X = c0 * 102.4f;
    float Y = c1 * 102.4f - 51.2f;
    float Z = -5.0f;
    float tx = calib[0] * X + calib[1] * Y + calib[2] * Z + calib[3];
    float ty = calib[4] * X + calib[5] * Y + calib[6] * Z + calib[7];
    float nx = (tx + 51.2f) * (1.0f / 102.4f);
    float ny = (ty + 51.2f) * (1.0f / 102.4f);
    float4 v = make_float4(nx, ny, c2, c3);
    *(float4*)&out[off + ((size_t)l * N + NV + k) * 4] = v;
}

// ---------------- inf reference gather + sigmoid/transform/inv-sigmoid ----------------
__device__ __forceinline__ float inv_sig(float v) {
    v = fminf(fmaxf(v, 0.0f), 1.0f);
    float x1 = fmaxf(v, 1e-5f);
    float x2 = fmaxf(1.0f - v, 1e-5f);
    return logf(x1 / x2);
}

__global__ void k_inf_ref(const float* __restrict__ src, const int* __restrict__ bbox,
                          const float* __restrict__ calib,
                          float* __restrict__ out,
                          int NI, int NV, int K, int off) {
    int k = blockIdx.x * blockDim.x + threadIdx.x;
    if (k >= K) return;
    int box = bbox[k]; box = max(0, min(box, NI - 1));
    const float* s = src + (size_t)box * 4;
    float r0 = s[0], r1 = s[1], r2 = s[2], r3 = s[3];
    float sx = 1.0f / (1.0f + expf(-r0));
    float sy = 1.0f / (1.0f + expf(-r1));
    float X = sx * 102.4f;
    float Y = sy * 102.4f - 51.2f;
    float Z = -1.0f;
    float tx = calib[0] * X + calib[1] * Y + calib[2] * Z + calib[3];
    float ty = calib[4] * X + calib[5] * Y + calib[6] * Z + calib[7];
    float nx = (tx + 51.2f) * (1.0f / 102.4f);
    float ny = (ty + 51.2f) * (1.0f / 102.4f);
    float4 v = make_float4(inv_sig(nx), inv_sig(ny), r2, r3);
    *(float4*)&out[off + ((size_t)NV + k) * 4] = v;
}

// ---------------- MFMA GEMM: out[row][col] = q[bbox[row]] . W[:,col] + bvec[col] ----
// block = 256 (4 waves); wave w owns cols [64w,64w+64) of a 64-row chunk.
// 16x16x32 bf16 MFMA, zero LDS, zero barriers. A loaded f32 from gathered q rows
// and converted in-register; B loaded bf16 from pre-transposed Wt (k-contiguous).
__device__ __forceinline__ bf16x8 cvt8(float4 f0, float4 f1) {
    bf16x8 r;
    r[0] = (__bf16)f0.x; r[1] = (__bf16)f0.y; r[2] = (__bf16)f0.z; r[3] = (__bf16)f0.w;
    r[4] = (__bf16)f1.x; r[5] = (__bf16)f1.y; r[6] = (__bf16)f1.z; r[7] = (__bf16)f1.w;
    return r;
}

__global__ __launch_bounds__(256) void k_gemm_mfma(
        const float* __restrict__ q0, const float* __restrict__ q1,
        const int* __restrict__ bbox,
        const __bf16* __restrict__ Wt0, const __bf16* __restrict__ Wt1,
        const float* __restrict__ bvec0, const float* __restrict__ bvec1,
        float* __restrict__ out, int NI, int K, int off0, int off1) {
    int which = blockIdx.y;
    const float* q      = which ? q1 : q0;
    const __bf16* Wt    = which ? Wt1 : Wt0;
    const float* bvec   = which ? bvec1 : bvec0;
    int out_off         = which ? off1 : off0;

    int tid  = threadIdx.x;
    int w    = tid >> 6;        // wave id = col group (0..3)
    int lane = tid & 63;
    int lo16 = lane & 15;
    int kg   = lane >> 4;       // k-group 0..3

    int r0 = blockIdx.x * 64;

    const float* aptr[4];
#pragma unroll
    for (int t = 0; t < 4; ++t) {
        int row = r0 + 16 * t + lo16;
        int rc = min(row, K - 1);
        int box = bbox[rc]; box = max(0, min(box, NI - 1));
        aptr[t] = q + (size_t)box * EMBED + kg * 8;
    }
    const __bf16* bptr[4];
#pragma unroll
    for (int t = 0; t < 4; ++t) {
        int col = w * 64 + 16 * t + lo16;
        bptr[t] = Wt + (size_t)col * EMBED + kg * 8;
    }

    f32x4 acc[4][4];
#pragma unroll
    for (int ct = 0; ct < 4; ++ct) {
        float bv = bvec[w * 64 + 16 * ct + lo16];
#pragma unroll
        for (int rt = 0; rt < 4; ++rt) {
            acc[rt][ct][0] = bv; acc[rt][ct][1] = bv; acc[rt][ct][2] = bv; acc[rt][ct][3] = bv;
        }
    }

    for (int s = 0; s < 8; ++s) {   // K = 8 steps x 32
        bf16x8 a[4], b[4];
#pragma unroll
        for (int t = 0; t < 4; ++t) {
            float4 f0 = *(const float4*)(aptr[t] + s * 32);
            float4 f1 = *(const float4*)(aptr[t] + s * 32 + 4);
            a[t] = cvt8(f0, f1);
            b[t] = *(const bf16x8*)(bptr[t] + s * 32);
        }
#pragma unroll
        for (int rt = 0; rt < 4; ++rt)
#pragma unroll
            for (int ct = 0; ct < 4; ++ct)
                acc[rt][ct] = __builtin_amdgcn_mfma_f32_16x16x32_bf16(a[rt], b[ct], acc[rt][ct], 0, 0, 0);
    }

#pragma unroll
    for (int rt = 0; rt < 4; ++rt) {
#pragma unroll
        for (int reg = 0; reg < 4; ++reg) {
            int row = r0 + 16 * rt + kg * 4 + reg;   // C/D: row=(lane>>4)*4+reg
            if (row < K) {
#pragma unroll
                for (int ct = 0; ct < 4; ++ct) {
                    int col = w * 64 + 16 * ct + lo16; // C/D: col=lane&15
                    out[out_off + (size_t)row * EMBED + col] = acc[rt][ct][reg];
                }
            }
        }
    }
}

extern "C" void kernel_launch(void* const* d_in, const int* in_sizes, int n_in,
                              void* d_out, int out_size, void* d_ws, size_t ws_size,
                              hipStream_t stream) {
    const float* inf_cls   = (const float*)d_in[0];
    const float* inf_coord = (const float*)d_in[1];
    const float* inf_q     = (const float*)d_in[2];
    const float* inf_qp    = (const float*)d_in[3];
    const float* inf_ref   = (const float*)d_in[4];
    const float* veh_cls   = (const float*)d_in[5];
    const float* veh_coord = (const float*)d_in[6];
    const float* veh_q     = (const float*)d_in[7];
    const float* veh_qp    = (const float*)d_in[8];
    const float* veh_ref   = (const float*)d_in[9];
    const float* rt        = (const float*)d_in[10];
    const float* W0        = (const float*)d_in[11];
    const float* b0        = (const float*)d_in[12];
    const float* W1        = (const float*)d_in[13];
    const float* b1        = (const float*)d_in[14];
    float* out = (float*)d_out;

    int NI = in_sizes[0] / (LL * 3);
    int NV = in_sizes[5] / (LL * 3);
    int N  = out_size / 558;          // 558 = 6*3 + 6*4 + 256 + 256 + 4
    int K  = N - NV;

    // output section element-offsets (f32 elements)
    int off_cls   = 0;
    int off_coord = LL * N * 3;
    int off_q     = off_coord + LL * N * 4;
    int off_qp    = off_q + N * EMBED;
    int off_ref   = off_qp + N * EMBED;

    // workspace layout
    char* ws = (char*)d_ws;
    float* calib = (float*)(ws);             // 16 f
    float* bvec0 = (float*)(ws + 128);       // 256 f
    float* bvec1 = (float*)(ws + 1152);      // 256 f
    int*   cnt   = (int*)(ws + 2176);
    int*   bbox  = (int*)(ws + 2304);        // up to NI*3 ints (96 KB)
    __bf16* Wt0  = (__bf16*)(ws + 131072);   // 128 KB
    __bf16* Wt1  = (__bf16*)(ws + 262144);   // 128 KB

    hipLaunchKernelGGL(k_calib, dim3(1), dim3(1), 0, stream, rt, calib);
    hipLaunchKernelGGL(k_select, dim3(1), dim3(1024), 0, stream,
                       inf_cls + (size_t)(LL - 1) * NI * 3, NI * 3, bbox, cnt);
    hipLaunchKernelGGL(k_bvec, dim3(2), dim3(EMBED), 0, stream,
                       calib, W0, b0, W1, b1, bvec0, bvec1);
    hipLaunchKernelGGL(k_wprep, dim3(EMBED, 2), dim3(EMBED), 0, stream, W0, W1, Wt0, Wt1);

    // fused veh copies
    {
        CopyJobs J;
        J.src[0] = veh_cls;   J.n4[0] = LL * NV * 3 / 4; J.off[0] = off_cls;
        J.perLay4[0] = NV * 3 / 4; J.layStride[0] = N * 3;
        J.src[1] = veh_coord; J.n4[1] = LL * NV * 4 / 4; J.off[1] = off_coord;
        J.perLay4[1] = NV * 4 / 4; J.layStride[1] = N * 4;
        J.src[2] = veh_q;     J.n4[2] = NV * EMBED / 4;  J.off[2] = off_q;
        J.perLay4[2] = J.n4[2]; J.layStride[2] = 0;
        J.src[3] = veh_qp;    J.n4[3] = NV * EMBED / 4;  J.off[3] = off_qp;
        J.perLay4[3] = J.n4[3]; J.layStride[3] = 0;
        J.src[4] = veh_ref;   J.n4[4] = NV * 4 / 4;      J.off[4] = off_ref;
        J.perLay4[4] = J.n4[4]; J.layStride[4] = 0;
        int maxn4 = J.n4[2];
        for (int j = 0; j < 5; ++j) if (J.n4[j] > maxn4) maxn4 = J.n4[j];
        hipLaunchKernelGGL(k_vehcopy, dim3((maxn4 + 255) / 256, 5), dim3(256), 0, stream, J, out);
    }

    if (K > 0) {
        hipLaunchKernelGGL(k_inf_cls, dim3((K * 3 + 255) / 256, LL), dim3(256), 0, stream,
                           inf_cls, bbox, out, NI, NV, K, N, off_cls);
        hipLaunchKernelGGL(k_inf_coord, dim3((K + 255) / 256, LL), dim3(256), 0, stream,
                           inf_coord, bbox, calib, out, NI, NV, K, N, off_coord);
        hipLaunchKernelGGL(k_inf_ref, dim3((K + 255) / 256), dim3(256), 0, stream,
                           inf_ref, bbox, calib, out, NI, NV, K, off_ref);
        int gb = (K + 63) / 64;
        hipLaunchKernelGGL(k_gemm_mfma, dim3(gb, 2), dim3(256), 0, stream,
                           inf_q, inf_qp, bbox, Wt0, Wt1, bvec0, bvec1,
                           out, NI, K, off_q + NV * EMBED, off_qp + NV * EMBED);
    }
}

// Round 4
// 67.606 us; speedup vs baseline: 2.9761x; 1.3589x over previous
//
#include <hip/hip_runtime.h>
#include <hip/hip_bf16.h>

#define EMBED 256
#define LL 6   // layers

typedef __attribute__((ext_vector_type(8))) __bf16 bf16x8;
typedef __attribute__((ext_vector_type(4))) float f32x4;

// sigmoid(x) > 0.05  <=>  x > -ln(19)
#define SEL_THR (-2.9444389791664403f)

// ================= K1: calib (thread 0) + predicate/compaction, 1 block =====
// Thread t owns contiguous elements [t*PT, t*PT+PT), PT rounded up to x4,
// cached in registers (<=16 float4). One shuffle scan + cross-wave LDS scan.
__global__ __launch_bounds__(1024) void k_select_calib(
        const float* __restrict__ cls, int n,
        const float* __restrict__ rt, float* __restrict__ calib,
        int* __restrict__ bbox, int* __restrict__ cnt) {
    __shared__ int warpCnt[16];
    int tid = threadIdx.x;
    int wid = tid >> 6, lane = tid & 63;

    if (tid == 0) {   // ---- calib = inv(rt^T), double precision ----
        double a[4][8];
        for (int i = 0; i < 4; ++i)
            for (int j = 0; j < 4; ++j) {
                a[i][j]     = (double)rt[j * 4 + i];
                a[i][4 + j] = (i == j) ? 1.0 : 0.0;
            }
        for (int c = 0; c < 4; ++c) {
            int p = c; double best = fabs(a[c][c]);
            for (int r = c + 1; r < 4; ++r) { double v = fabs(a[r][c]); if (v > best) { best = v; p = r; } }
            if (p != c) for (int j = 0; j < 8; ++j) { double t = a[c][j]; a[c][j] = a[p][j]; a[p][j] = t; }
            double inv = 1.0 / a[c][c];
            for (int j = 0; j < 8; ++j) a[c][j] *= inv;
            for (int r = 0; r < 4; ++r) if (r != c) {
                double f = a[r][c];
                for (int j = 0; j < 8; ++j) a[r][j] -= f * a[c][j];
            }
        }
        for (int i = 0; i < 4; ++i)
            for (int j = 0; j < 4; ++j) calib[i * 4 + j] = (float)a[i][4 + j];
    }

    int PT = ((n + 1023) / 1024 + 3) & ~3;   // elems per thread, x4 (<=64 assumed)
    int PT4 = PT >> 2;                        // float4 per thread (<=16)
    int start = tid * PT;

    float4 v[16];
#pragma unroll
    for (int j4 = 0; j4 < 16; ++j4) {
        if (j4 < PT4) {
            int s = start + j4 * 4;
            if (s + 4 <= n) {
                v[j4] = *(const float4*)&cls[s];
            } else {
                float4 t; t.x = t.y = t.z = t.w = -1e30f;
                if (s + 0 < n) t.x = cls[s + 0];
                if (s + 1 < n) t.y = cls[s + 1];
                if (s + 2 < n) t.z = cls[s + 2];
                if (s + 3 < n) t.w = cls[s + 3];
                v[j4] = t;
            }
        }
    }
    int c = 0;
#pragma unroll
    for (int j4 = 0; j4 < 16; ++j4) {
        if (j4 < PT4) {
            c += (v[j4].x > SEL_THR) + (v[j4].y > SEL_THR) +
                 (v[j4].z > SEL_THR) + (v[j4].w > SEL_THR);
        }
    }
    // wave inclusive scan
    int incl = c;
#pragma unroll
    for (int off = 1; off < 64; off <<= 1) {
        int u = __shfl_up(incl, off, 64);
        if (lane >= off) incl += u;
    }
    if (lane == 63) warpCnt[wid] = incl;
    __syncthreads();
    int base = 0;
    for (int w2 = 0; w2 < wid; ++w2) base += warpCnt[w2];
    int pos = base + incl - c;   // exclusive prefix

    // scatter (in element order; per-thread range is contiguous)
#pragma unroll
    for (int j4 = 0; j4 < 16; ++j4) {
        if (j4 < PT4) {
            int s = start + j4 * 4;
            if (s + 0 < n && v[j4].x > SEL_THR) bbox[pos++] = (s + 0) / 3;
            if (s + 1 < n && v[j4].y > SEL_THR) bbox[pos++] = (s + 1) / 3;
            if (s + 2 < n && v[j4].z > SEL_THR) bbox[pos++] = (s + 2) / 3;
            if (s + 3 < n && v[j4].w > SEL_THR) bbox[pos++] = (s + 3) / 3;
        }
    }
    if (tid == 0) {
        int tot = 0;
        for (int w2 = 0; w2 < 16; ++w2) tot += warpCnt[w2];
        *cnt = tot;
    }
}

// ================= K2: tiled W transpose->bf16 + bvec =======================
// grid (4,4,2); block (x,y,z): 64k x 64col tile of W[z]; block (0,0,z) adds bvec.
__global__ __launch_bounds__(256) void k_prep(
        const float* __restrict__ W0, const float* __restrict__ W1,
        const float* __restrict__ b0, const float* __restrict__ b1,
        const float* __restrict__ calib,
        __bf16* __restrict__ Wt0, __bf16* __restrict__ Wt1,
        float* __restrict__ bvec0, float* __restrict__ bvec1) {
    int which = blockIdx.z;
    const float* W = which ? W1 : W0;
    __bf16* Wt     = which ? Wt1 : Wt0;
    int k0 = blockIdx.x * 64, c0 = blockIdx.y * 64;
    __shared__ float T[64][65];
    int tid = threadIdx.x;
#pragma unroll
    for (int i = 0; i < 16; ++i) {
        int idx = i * 256 + tid;
        int kk = idx >> 6, cc = idx & 63;
        T[kk][cc] = W[(size_t)(k0 + kk) * EMBED + c0 + cc];
    }
    __syncthreads();
#pragma unroll
    for (int i = 0; i < 16; ++i) {
        int idx = i * 256 + tid;
        int cc = idx >> 6, kk = idx & 63;
        Wt[(size_t)(c0 + cc) * EMBED + k0 + kk] = (__bf16)T[kk][cc];
    }
    if (blockIdx.x == 0 && blockIdx.y == 0) {
        const float* b = which ? b1 : b0;
        float* o       = which ? bvec1 : bvec0;
        float s = b[tid];
#pragma unroll
        for (int u = 0; u < 9; ++u) {
            float r = calib[(u / 3) * 4 + (u % 3)];
            s += r * W[(EMBED + u) * EMBED + tid];
        }
        o[tid] = s;
    }
}

// ================= K3: fused veh copies + inf gathers/transforms ============
struct Plan {
    const float* src[8];   // 0..4 veh{cls,coord,q,qp,ref}, 5 inf_cls, 6 inf_coord, 7 inf_ref
    int start[9];          // block prefix per job
    int n4[5];             // float4 counts, copy jobs
    int dstOff[8];         // f32-element dst base
    int perLay4[2];        // jobs 0,1: float4 per layer
    int layStride[2];      // jobs 0,1: dst layer stride (f32)
    int K, NI, NV, N;
};

__device__ __forceinline__ float inv_sig(float v) {
    v = fminf(fmaxf(v, 0.0f), 1.0f);
    float x1 = fmaxf(v, 1e-5f);
    float x2 = fmaxf(1.0f - v, 1e-5f);
    return logf(x1 / x2);
}

__global__ __launch_bounds__(256) void k_fused(Plan P, const int* __restrict__ bbox,
                                               const float* __restrict__ calib,
                                               float* __restrict__ out) {
    int bx = blockIdx.x;
    int j = 0;
    while (bx >= P.start[j + 1]) ++j;
    int lb  = bx - P.start[j];
    int tid = threadIdx.x;

    if (j < 5) {                       // ---- plain copies, 4 x float4/thread ----
#pragma unroll
        for (int it = 0; it < 4; ++it) {
            int i4 = lb * 1024 + it * 256 + tid;
            if (i4 < P.n4[j]) {
                float4 v = *(const float4*)&P.src[j][(size_t)i4 * 4];
                size_t d;
                if (j < 2) {
                    int l = i4 / P.perLay4[j];
                    int r = i4 - l * P.perLay4[j];
                    d = (size_t)P.dstOff[j] + (size_t)l * P.layStride[j] + (size_t)r * 4;
                } else {
                    d = (size_t)P.dstOff[j] + (size_t)i4 * 4;
                }
                *(float4*)&out[d] = v;
            }
        }
        return;
    }

    int k = lb * 256 + tid;
    if (k >= P.K) return;
    int box = bbox[k]; box = max(0, min(box, P.NI - 1));

    if (j == 5) {                      // ---- inf classes gather, 6 layers ----
        const float* s0 = P.src[5];
#pragma unroll
        for (int l = 0; l < LL; ++l) {
            const float* s = s0 + ((size_t)l * P.NI + box) * 3;
            size_t d = (size_t)P.dstOff[5] + ((size_t)l * P.N + P.NV) * 3 + (size_t)k * 3;
            out[d + 0] = s[0]; out[d + 1] = s[1]; out[d + 2] = s[2];
        }
    } else if (j == 6) {               // ---- inf coords gather+transform ----
        float c00 = calib[0], c01 = calib[1], c03 = calib[3];
        float c10 = calib[4], c11 = calib[5], c13 = calib[7];
        float zx = calib[2] * -5.0f, zy = calib[6] * -5.0f;
#pragma unroll
        for (int l = 0; l < LL; ++l) {
            float4 s = *(const float4*)&P.src[6][((size_t)l * P.NI + box) * 4];
            float X = s.x * 102.4f;
            float Y = s.y * 102.4f - 51.2f;
            float tx = c00 * X + c01 * Y + zx + c03;
            float ty = c10 * X + c11 * Y + zy + c13;
            float4 v = make_float4((tx + 51.2f) * (1.0f / 102.4f),
                                   (ty + 51.2f) * (1.0f / 102.4f), s.z, s.w);
            *(float4*)&out[(size_t)P.dstOff[6] + ((size_t)l * P.N + P.NV + k) * 4] = v;
        }
    } else {                           // ---- inf reference ----
        float4 s = *(const float4*)&P.src[7][(size_t)box * 4];
        float sx = 1.0f / (1.0f + expf(-s.x));
        float sy = 1.0f / (1.0f + expf(-s.y));
        float X = sx * 102.4f;
        float Y = sy * 102.4f - 51.2f;
        float tx = calib[0] * X + calib[1] * Y + calib[2] * -1.0f + calib[3];
        float ty = calib[4] * X + calib[5] * Y + calib[6] * -1.0f + calib[7];
        float4 v = make_float4(inv_sig((tx + 51.2f) * (1.0f / 102.4f)),
                               inv_sig((ty + 51.2f) * (1.0f / 102.4f)), s.z, s.w);
        *(float4*)&out[(size_t)P.dstOff[7] + ((size_t)P.NV + k) * 4] = v;
    }
}

// ================= K4: MFMA GEMM (verified round 3) =========================
__device__ __forceinline__ bf16x8 cvt8(float4 f0, float4 f1) {
    bf16x8 r;
    r[0] = (__bf16)f0.x; r[1] = (__bf16)f0.y; r[2] = (__bf16)f0.z; r[3] = (__bf16)f0.w;
    r[4] = (__bf16)f1.x; r[5] = (__bf16)f1.y; r[6] = (__bf16)f1.z; r[7] = (__bf16)f1.w;
    return r;
}

__global__ __launch_bounds__(256) void k_gemm_mfma(
        const float* __restrict__ q0, const float* __restrict__ q1,
        const int* __restrict__ bbox,
        const __bf16* __restrict__ Wt0, const __bf16* __restrict__ Wt1,
        const float* __restrict__ bvec0, const float* __restrict__ bvec1,
        float* __restrict__ out, int NI, int K, int off0, int off1) {
    int which = blockIdx.y;
    const float* q    = which ? q1 : q0;
    const __bf16* Wt  = which ? Wt1 : Wt0;
    const float* bvec = which ? bvec1 : bvec0;
    int out_off       = which ? off1 : off0;

    int tid  = threadIdx.x;
    int w    = tid >> 6;
    int lane = tid & 63;
    int lo16 = lane & 15;
    int kg   = lane >> 4;

    int r0 = blockIdx.x * 64;

    const float* aptr[4];
#pragma unroll
    for (int t = 0; t < 4; ++t) {
        int row = r0 + 16 * t + lo16;
        int rc = min(row, K - 1);
        int box = bbox[rc]; box = max(0, min(box, NI - 1));
        aptr[t] = q + (size_t)box * EMBED + kg * 8;
    }
    const __bf16* bptr[4];
#pragma unroll
    for (int t = 0; t < 4; ++t) {
        int col = w * 64 + 16 * t + lo16;
        bptr[t] = Wt + (size_t)col * EMBED + kg * 8;
    }

    f32x4 acc[4][4];
#pragma unroll
    for (int ct = 0; ct < 4; ++ct) {
        float bv = bvec[w * 64 + 16 * ct + lo16];
#pragma unroll
        for (int rt = 0; rt < 4; ++rt) {
            acc[rt][ct][0] = bv; acc[rt][ct][1] = bv; acc[rt][ct][2] = bv; acc[rt][ct][3] = bv;
        }
    }

    for (int s = 0; s < 8; ++s) {
        bf16x8 a[4], b[4];
#pragma unroll
        for (int t = 0; t < 4; ++t) {
            float4 f0 = *(const float4*)(aptr[t] + s * 32);
            float4 f1 = *(const float4*)(aptr[t] + s * 32 + 4);
            a[t] = cvt8(f0, f1);
            b[t] = *(const bf16x8*)(bptr[t] + s * 32);
        }
#pragma unroll
        for (int rt = 0; rt < 4; ++rt)
#pragma unroll
            for (int ct = 0; ct < 4; ++ct)
                acc[rt][ct] = __builtin_amdgcn_mfma_f32_16x16x32_bf16(a[rt], b[ct], acc[rt][ct], 0, 0, 0);
    }

#pragma unroll
    for (int rt = 0; rt < 4; ++rt) {
#pragma unroll
        for (int reg = 0; reg < 4; ++reg) {
            int row = r0 + 16 * rt + kg * 4 + reg;
            if (row < K) {
#pragma unroll
                for (int ct = 0; ct < 4; ++ct) {
                    int col = w * 64 + 16 * ct + lo16;
                    out[out_off + (size_t)row * EMBED + col] = acc[rt][ct][reg];
                }
            }
        }
    }
}

extern "C" void kernel_launch(void* const* d_in, const int* in_sizes, int n_in,
                              void* d_out, int out_size, void* d_ws, size_t ws_size,
                              hipStream_t stream) {
    const float* inf_cls   = (const float*)d_in[0];
    const float* inf_coord = (const float*)d_in[1];
    const float* inf_q     = (const float*)d_in[2];
    const float* inf_qp    = (const float*)d_in[3];
    const float* inf_ref   = (const float*)d_in[4];
    const float* veh_cls   = (const float*)d_in[5];
    const float* veh_coord = (const float*)d_in[6];
    const float* veh_q     = (const float*)d_in[7];
    const float* veh_qp    = (const float*)d_in[8];
    const float* veh_ref   = (const float*)d_in[9];
    const float* rt        = (const float*)d_in[10];
    const float* W0        = (const float*)d_in[11];
    const float* b0        = (const float*)d_in[12];
    const float* W1        = (const float*)d_in[13];
    const float* b1        = (const float*)d_in[14];
    float* out = (float*)d_out;

    int NI = in_sizes[0] / (LL * 3);
    int NV = in_sizes[5] / (LL * 3);
    int N  = out_size / 558;
    int K  = N - NV;

    int off_cls   = 0;
    int off_coord = LL * N * 3;
    int off_q     = off_coord + LL * N * 4;
    int off_qp    = off_q + N * EMBED;
    int off_ref   = off_qp + N * EMBED;

    char* ws = (char*)d_ws;
    float* calib = (float*)(ws);
    float* bvec0 = (float*)(ws + 128);
    float* bvec1 = (float*)(ws + 1152);
    int*   cnt   = (int*)(ws + 2176);
    int*   bbox  = (int*)(ws + 2304);
    __bf16* Wt0  = (__bf16*)(ws + 131072);
    __bf16* Wt1  = (__bf16*)(ws + 262144);

    // K1
    hipLaunchKernelGGL(k_select_calib, dim3(1), dim3(1024), 0, stream,
                       inf_cls + (size_t)(LL - 1) * NI * 3, NI * 3, rt, calib, bbox, cnt);
    // K2
    hipLaunchKernelGGL(k_prep, dim3(4, 4, 2), dim3(256), 0, stream,
                       W0, W1, b0, b1, calib, Wt0, Wt1, bvec0, bvec1);
    // K3
    {
        Plan P;
        P.src[0] = veh_cls;   P.src[1] = veh_coord; P.src[2] = veh_q;
        P.src[3] = veh_qp;    P.src[4] = veh_ref;
        P.src[5] = inf_cls;   P.src[6] = inf_coord; P.src[7] = inf_ref;
        P.n4[0] = LL * NV * 3 / 4;  P.n4[1] = LL * NV * 4 / 4;
        P.n4[2] = NV * EMBED / 4;   P.n4[3] = NV * EMBED / 4;  P.n4[4] = NV * 4 / 4;
        P.dstOff[0] = off_cls;   P.dstOff[1] = off_coord; P.dstOff[2] = off_q;
        P.dstOff[3] = off_qp;    P.dstOff[4] = off_ref;
        P.dstOff[5] = off_cls;   P.dstOff[6] = off_coord; P.dstOff[7] = off_ref;
        P.perLay4[0] = NV * 3 / 4;  P.perLay4[1] = NV * 4 / 4;
        P.layStride[0] = N * 3;     P.layStride[1] = N * 4;
        P.K = K; P.NI = NI; P.NV = NV; P.N = N;
        int nb[8];
        for (int j = 0; j < 5; ++j) nb[j] = (P.n4[j] + 1023) / 1024;
        int gblk = (K + 255) / 256;
        nb[5] = gblk; nb[6] = gblk; nb[7] = gblk;
        P.start[0] = 0;
        for (int j = 0; j < 8; ++j) P.start[j + 1] = P.start[j] + (nb[j] > 0 ? nb[j] : 0);
        if (K > 0 ? P.start[8] > 0 : P.start[5] > 0) {
            int totalBlocks = (K > 0) ? P.start[8] : P.start[5];
            hipLaunchKernelGGL(k_fused, dim3(totalBlocks), dim3(256), 0, stream,
                               P, bbox, calib, out);
        }
    }
    // K4
    if (K > 0) {
        int gb = (K + 63) / 64;
        hipLaunchKernelGGL(k_gemm_mfma, dim3(gb, 2), dim3(256), 0, stream,
                           inf_q, inf_qp, bbox, Wt0, Wt1, bvec0, bvec1,
                           out, NI, K, off_q + NV * EMBED, off_qp + NV * EMBED);
    }
}